// Round 8
// baseline (141.770 us; speedup 1.0000x reference)
//
#include <hip/hip_runtime.h>
#include <hip/hip_bf16.h>

#define B_    8
#define CIN_  256
#define CC_   128
#define COUT_ 64
#define HP_   68            // f padded: 64 + 2 + 2
#define HPX_  (HP_ * HP_)   // 4624
#define XQW_  66            // x padded: 64 + 1 + 1
#define XQPX_ (XQW_ * XQW_) // 4356

typedef __attribute__((ext_vector_type(8))) short bh8;
typedef __attribute__((ext_vector_type(4))) float f4;

__device__ __forceinline__ ushort f2bf(float f) {   // RNE
    uint u = __float_as_uint(f);
    return (ushort)((u + 0x7fffu + ((u >> 16) & 1u)) >> 16);
}
__device__ __forceinline__ float bf2f(ushort s) {
    return __uint_as_float(((uint)s) << 16);
}
__device__ __forceinline__ short f2bf_c(float f) {  // compiler path -> v_cvt_pk fusion
    __hip_bfloat16 h = __float2bfloat16(f);
    short s;
    __builtin_memcpy(&s, &h, 2);
    return s;
}

// ---- merged prep: zero pad-ring of fpad_t + transpose/quantize both weights
__global__ __launch_bounds__(256) void prep_misc(const float* __restrict__ w_ext,
                                                 const float* __restrict__ w_reg,
                                                 short* __restrict__ wg,
                                                 short* __restrict__ wa,
                                                 ushort* __restrict__ fpad_t) {
    int e = blockIdx.x * 256 + threadIdx.x;
    if (e < 67584) {
        int seg = e & 15;
        int t = e >> 4;
        int b = t / 528, rp = t - b * 528;
        int i, j;
        if (rp < 136) { i = rp / 68; j = rp - (rp / 68) * 68; }
        else if (rp < 272) { int r = rp - 136; i = 66 + r / 68; j = r - (r / 68) * 68; }
        else { int r = rp - 272; i = 2 + (r >> 2); int c = r & 3; j = (c < 2) ? c : c + 64; }
        uint4 z; z.x = 0u; z.y = 0u; z.z = 0u; z.w = 0u;
        *(uint4*)&fpad_t[(((size_t)b * HPX_) + i * HP_ + j) * 128 + seg * 8] = z;
        return;
    }
    e -= 67584;
    if (e < 294912) {
        int ci = e & 31;
        int t  = e >> 5;
        int cc = t & 127;
        int t2 = t >> 7;
        int rs = t2 % 9, cb = t2 / 9;
        wg[e] = (short)f2bf(w_ext[(cc * CIN_ + cb * 32 + ci) * 9 + rs]);
        return;
    }
    e -= 294912;
    if (e < 204800) {
        int ci = e & 31;
        int o  = (e >> 5) & 63;
        int rest = e >> 11;
        int k = rest % 25, q = rest / 25;
        wa[e] = (short)f2bf(w_reg[(o * CC_ + q * 32 + ci) * 25 + k]);
    }
}

// ---- prep: x fp32 [b][256ci][64][64] -> bf16 xq[b][cb 8][66][66][32ci], zero ring
__global__ __launch_bounds__(256) void prep_x(const float* __restrict__ x,
                                              ushort* __restrict__ xq) {
    __shared__ float xt[2][32][65];   // [row-pair][ci][xx] (65: bank-spread)
    const int tid = threadIdx.x;
    const int rp = blockIdx.x, cb = blockIdx.y, b = blockIdx.z;

#pragma unroll
    for (int rr = 0; rr < 2; ++rr) {
        int y = rp * 2 + rr - 1;
        if ((unsigned)y < 64u) {
            int xx = tid & 63, wv = tid >> 6;
#pragma unroll
            for (int it = 0; it < 8; ++it) {
                int ci = it * 4 + wv;
                xt[rr][ci][xx] = x[(((size_t)(b * CIN_ + cb * 32 + ci)) * 64 + y) * 64 + xx];
            }
        }
    }
    __syncthreads();

    for (int e = tid; e < 528; e += 256) {           // 2 rows x 66 hc x 4 segs
        int rr = e / 264, t = e - rr * 264;
        int hc = t >> 2, seg = t & 3;
        int y = rp * 2 + rr - 1, xx = hc - 1;
        uint pk[4] = {0u, 0u, 0u, 0u};
        if ((unsigned)y < 64u && (unsigned)xx < 64u) {
#pragma unroll
            for (int i = 0; i < 4; ++i) {
                uint lo = f2bf(xt[rr][seg * 8 + i * 2][xx]);
                uint hi = f2bf(xt[rr][seg * 8 + i * 2 + 1][xx]);
                pk[i] = lo | (hi << 16);
            }
        }
        uint4 v; v.x = pk[0]; v.y = pk[1]; v.z = pk[2]; v.w = pk[3];
        *(uint4*)&xq[((((size_t)(b * 8 + cb)) * XQPX_) + (rp * 2 + rr) * XQW_ + hc) * 32 + seg * 8] = v;
    }
}

// ---- conv staging: pure b128 copies from xq
__device__ __forceinline__ void stage_xq(const ushort* __restrict__ xq, short* __restrict__ dst,
                                         int b, int cb, int i0, int j0, int tid) {
    const ushort* base = xq + (((size_t)(b * 8 + cb)) * XQPX_) * 32;
    for (int e = tid; e < 400; e += 256) {           // 100 hpx x 4 segs of 8ci
        int hp = e >> 2, seg = e & 3;
        int hr = hp / 10, hc = hp - hr * 10;
        const ushort* src = base + ((size_t)((i0 + hr) * XQW_ + (j0 + hc))) * 32 + seg * 8;
        *(bh8*)&dst[hp * 72 + seg * 8] = *(const bh8*)src;
    }
}

// ---- conv 3x3 bf16 MFMA; 4 waves: wave = 128cc x 16px (m=8, n=1), A-prefetch ring
__global__ __launch_bounds__(256) void conv3x3_mfma(const ushort* __restrict__ xq,
                                                    const short* __restrict__ wg,
                                                    const float* __restrict__ bext,
                                                    ushort* __restrict__ fpad_t) {
    __shared__ __align__(16) short xh[2][100 * 72];   // 28.8 KB double-buffered
    const int tid = threadIdx.x;
    const int lane = tid & 63, wv = tid >> 6;
    const int j0 = blockIdx.x * 8, i0 = blockIdx.y * 8, b = blockIdx.z;
    const int l15 = lane & 15, kg = lane >> 4;
    const int px = wv * 16 + l15, pi = px >> 3, pj = px & 7;
    const int aoff = l15 * 32 + kg * 8;               // within [cc128][ci32]: mm*512 + aoff

    f4 acc[8] = {};
    bh8 aC[8], aN[8];

    stage_xq(xq, xh[0], b, 0, i0, j0, tid);
#pragma unroll
    for (int mm = 0; mm < 8; ++mm)                    // preload t=0 A-frags
        aC[mm] = *(const bh8*)(wg + mm * 512 + aoff);
    __syncthreads();

    for (int cb = 0; cb < 8; ++cb) {
        const int buf = cb & 1;
        if (cb < 7) stage_xq(xq, xh[buf ^ 1], b, cb + 1, i0, j0, tid);
#pragma unroll
        for (int rs = 0; rs < 9; ++rs) {
            const int r = rs / 3, s = rs % 3;
            const int t = cb * 9 + rs;
            const int tn = (t < 71) ? t + 1 : 71;
            const short* wb = wg + (size_t)tn * 4096;
#pragma unroll
            for (int mm = 0; mm < 8; ++mm)            // prefetch next-iter A (issued early)
                aN[mm] = *(const bh8*)(wb + mm * 512 + aoff);
            bh8 bb = *(const bh8*)&xh[buf][((pi + r) * 10 + (pj + s)) * 72 + kg * 8];
#pragma unroll
            for (int mm = 0; mm < 8; ++mm)
                acc[mm] = __builtin_amdgcn_mfma_f32_16x16x32_bf16(aC[mm], bb, acc[mm], 0, 0, 0);
#pragma unroll
            for (int mm = 0; mm < 8; ++mm) aC[mm] = aN[mm];
        }
        __syncthreads();
    }

    // epilogue: D row -> cc (kg*4+reg), col -> px; 4 cc packed -> 8B store
#pragma unroll
    for (int mm = 0; mm < 8; ++mm) {
        const int ccb = mm * 16 + kg * 4;
        float bv0 = bext[ccb + 0], bv1 = bext[ccb + 1];
        float bv2 = bext[ccb + 2], bv3 = bext[ccb + 3];
        size_t row = (size_t)b * HPX_ + (2 + i0 + pi) * HP_ + (2 + j0 + pj);
        uint lo = (uint)f2bf(acc[mm][0] + bv0) | ((uint)f2bf(acc[mm][1] + bv1) << 16);
        uint hi = (uint)f2bf(acc[mm][2] + bv2) | ((uint)f2bf(acc[mm][3] + bv3) << 16);
        uint2 pk; pk.x = lo; pk.y = hi;
        *(uint2*)&fpad_t[row * 128 + ccb] = pk;
    }
}

// ---- autocorr bf16 MFMA; 4 waves: wave = 64o x 16px (m=4, n=1), depth-2 A-prefetch
__global__ __launch_bounds__(256) void autocorr_mfma(const ushort* __restrict__ ft,
                                                     const short* __restrict__ wA,
                                                     const float* __restrict__ breg,
                                                     float* __restrict__ out) {
    __shared__ __align__(16) short flds[144 * 136];   // 39.2 KB
    const int tid = threadIdx.x;
    const int lane = tid & 63, wv = tid >> 6;
    const int j0 = blockIdx.x * 8, i0 = blockIdx.y * 8, b = blockIdx.z;
    const int l15 = lane & 15, kg = lane >> 4;
    const int px = wv * 16 + l15, pi = px >> 3, pj = px & 7;
    const int aoff = l15 * 32 + kg * 8;               // within [o64][ci32]: mm*512 + aoff

    for (int e = tid; e < 2304; e += 256) {           // 144 hpx x 16 segs
        int hp = e >> 4, seg = e & 15;
        int hr = hp / 12, hc = hp - hr * 12;
        const ushort* src = ft + ((size_t)b * HPX_ + (i0 + hr) * HP_ + (j0 + hc)) * 128 + seg * 8;
        *(bh8*)&flds[hp * 136 + seg * 8] = *(const bh8*)src;
    }

    f4 acc[4] = {};
    bh8 A0[4], A1[4], A2[4];
#pragma unroll
    for (int mm = 0; mm < 4; ++mm) {                  // preload t=0,1
        A0[mm] = *(const bh8*)(wA + mm * 512 + aoff);
        A1[mm] = *(const bh8*)(wA + 2048 + mm * 512 + aoff);
    }
    __syncthreads();

    const int base_off = (pi * 12 + pj) * 136 + kg * 8;
    const int cen_off  = ((pi + 2) * 12 + (pj + 2)) * 136 + kg * 8;

#pragma unroll 1
    for (int q = 0; q < 4; ++q) {
        bh8 c8 = *(const bh8*)&flds[cen_off + q * 32];
        float cen[8];
#pragma unroll
        for (int jj = 0; jj < 8; ++jj) cen[jj] = bf2f((ushort)c8[jj]);

#pragma unroll
        for (int k = 0; k < 25; ++k) {
            const int u = k / 5, v = k % 5;
            const int koff = (u * 12 + v) * 136;
            bh8 s8 = *(const bh8*)&flds[base_off + q * 32 + koff];
            // prefetch t+2 (issued before the VALU/MFMA of iteration t)
            int t = q * 25 + k;
            int tn = (t < 98) ? t + 2 : 99;
            const short* wb = wA + (size_t)tn * 2048;
#pragma unroll
            for (int mm = 0; mm < 4; ++mm)
                A2[mm] = *(const bh8*)(wb + mm * 512 + aoff);
            bh8 bbv;
#pragma unroll
            for (int jj = 0; jj < 8; ++jj)
                bbv[jj] = f2bf_c(bf2f((ushort)s8[jj]) * cen[jj]);
#pragma unroll
            for (int mm = 0; mm < 4; ++mm)
                acc[mm] = __builtin_amdgcn_mfma_f32_16x16x32_bf16(A0[mm], bbv, acc[mm], 0, 0, 0);
#pragma unroll
            for (int mm = 0; mm < 4; ++mm) { A0[mm] = A1[mm]; A1[mm] = A2[mm]; }
        }
    }

    // epilogue: D row -> o, col -> px
#pragma unroll
    for (int mm = 0; mm < 4; ++mm) {
#pragma unroll
        for (int reg = 0; reg < 4; ++reg) {
            int o = mm * 16 + kg * 4 + reg;
            out[(((size_t)(b * COUT_ + o)) * 64 + i0 + pi) * 64 + j0 + pj] =
                acc[mm][reg] + breg[o];
        }
    }
}

extern "C" void kernel_launch(void* const* d_in, const int* in_sizes, int n_in,
                              void* d_out, int out_size, void* d_ws, size_t ws_size,
                              hipStream_t stream) {
    const float* x     = (const float*)d_in[0];
    const float* w_ext = (const float*)d_in[1];
    const float* b_ext = (const float*)d_in[2];
    const float* w_reg = (const float*)d_in[3];
    const float* b_reg = (const float*)d_in[4];
    float* out = (float*)d_out;

    char* ws = (char*)d_ws;
    const size_t FPADT_BYTES = (size_t)B_ * HPX_ * 128 * 2;        // 9,469,952
    const size_t WG_BYTES    = (size_t)8 * 9 * 128 * 32 * 2;       // 589,824
    const size_t WA_BYTES    = (size_t)4 * 25 * 64 * 32 * 2;       // 409,600
    ushort* fpad_t = (ushort*)ws;
    short*  wgq    = (short*)(ws + FPADT_BYTES);
    short*  wa     = (short*)(ws + FPADT_BYTES + WG_BYTES);
    ushort* xq     = (ushort*)(ws + FPADT_BYTES + WG_BYTES + WA_BYTES);  // 17,842,176

    const int PREP_TOTAL = 67584 + 294912 + 204800;   // 567,296
    prep_misc<<<(PREP_TOTAL + 255) / 256, 256, 0, stream>>>(w_ext, w_reg, wgq, wa, fpad_t);

    dim3 pgrid(33, 8, 8);                             // row-pairs, cb, b
    prep_x<<<pgrid, 256, 0, stream>>>(x, xq);

    dim3 grid(8, 8, 8);
    conv3x3_mfma<<<grid, 256, 0, stream>>>(xq, wgq, b_ext, fpad_t);
    autocorr_mfma<<<grid, 256, 0, stream>>>(fpad_t, wa, b_reg, out);
}

// Round 9
// 82.713 us; speedup vs baseline: 1.7140x; 1.7140x over previous
//
#include <hip/hip_runtime.h>
#include <hip/hip_bf16.h>

#define B_    8
#define CIN_  256
#define CC_   128
#define COUT_ 64
#define HP_   68            // f padded: 64 + 2 + 2
#define HPX_  (HP_ * HP_)   // 4624
#define XQW_  66            // x padded: 64 + 1 + 1
#define XQPX_ (XQW_ * XQW_) // 4356

typedef __attribute__((ext_vector_type(8))) short bh8;
typedef __attribute__((ext_vector_type(4))) float f4;

__device__ __forceinline__ ushort f2bf(float f) {   // RNE
    uint u = __float_as_uint(f);
    return (ushort)((u + 0x7fffu + ((u >> 16) & 1u)) >> 16);
}
__device__ __forceinline__ float bf2f(ushort s) {
    return __uint_as_float(((uint)s) << 16);
}
__device__ __forceinline__ short f2bf_c(float f) {  // compiler path -> v_cvt_pk fusion
    __hip_bfloat16 h = __float2bfloat16(f);
    short s;
    __builtin_memcpy(&s, &h, 2);
    return s;
}

// ---- merged prep: zero pad-ring of fpad_t + transpose/quantize both weights
__global__ __launch_bounds__(256) void prep_misc(const float* __restrict__ w_ext,
                                                 const float* __restrict__ w_reg,
                                                 short* __restrict__ wg,
                                                 short* __restrict__ wa,
                                                 ushort* __restrict__ fpad_t) {
    int e = blockIdx.x * 256 + threadIdx.x;
    if (e < 67584) {
        int seg = e & 15;
        int t = e >> 4;
        int b = t / 528, rp = t - b * 528;
        int i, j;
        if (rp < 136) { i = rp / 68; j = rp - (rp / 68) * 68; }
        else if (rp < 272) { int r = rp - 136; i = 66 + r / 68; j = r - (r / 68) * 68; }
        else { int r = rp - 272; i = 2 + (r >> 2); int c = r & 3; j = (c < 2) ? c : c + 64; }
        uint4 z; z.x = 0u; z.y = 0u; z.z = 0u; z.w = 0u;
        *(uint4*)&fpad_t[(((size_t)b * HPX_) + i * HP_ + j) * 128 + seg * 8] = z;
        return;
    }
    e -= 67584;
    if (e < 294912) {
        int ci = e & 31;
        int t  = e >> 5;
        int cc = t & 127;
        int t2 = t >> 7;
        int rs = t2 % 9, cb = t2 / 9;
        wg[e] = (short)f2bf(w_ext[(cc * CIN_ + cb * 32 + ci) * 9 + rs]);
        return;
    }
    e -= 294912;
    if (e < 204800) {
        int ci = e & 31;
        int o  = (e >> 5) & 63;
        int rest = e >> 11;
        int k = rest % 25, q = rest / 25;
        wa[e] = (short)f2bf(w_reg[(o * CC_ + q * 32 + ci) * 25 + k]);
    }
}

// ---- prep: x fp32 [b][256ci][64][64] -> bf16 xq[b][cb 8][66][66][32ci], zero ring
__global__ __launch_bounds__(256) void prep_x(const float* __restrict__ x,
                                              ushort* __restrict__ xq) {
    __shared__ float xt[2][32][65];   // [row-pair][ci][xx] (65: bank-spread)
    const int tid = threadIdx.x;
    const int rp = blockIdx.x, cb = blockIdx.y, b = blockIdx.z;

#pragma unroll
    for (int rr = 0; rr < 2; ++rr) {
        int y = rp * 2 + rr - 1;
        if ((unsigned)y < 64u) {
            int xx = tid & 63, wv = tid >> 6;
#pragma unroll
            for (int it = 0; it < 8; ++it) {
                int ci = it * 4 + wv;
                xt[rr][ci][xx] = x[(((size_t)(b * CIN_ + cb * 32 + ci)) * 64 + y) * 64 + xx];
            }
        }
    }
    __syncthreads();

    for (int e = tid; e < 528; e += 256) {           // 2 rows x 66 hc x 4 segs
        int rr = e / 264, t = e - rr * 264;
        int hc = t >> 2, seg = t & 3;
        int y = rp * 2 + rr - 1, xx = hc - 1;
        uint pk[4] = {0u, 0u, 0u, 0u};
        if ((unsigned)y < 64u && (unsigned)xx < 64u) {
#pragma unroll
            for (int i = 0; i < 4; ++i) {
                uint lo = f2bf(xt[rr][seg * 8 + i * 2][xx]);
                uint hi = f2bf(xt[rr][seg * 8 + i * 2 + 1][xx]);
                pk[i] = lo | (hi << 16);
            }
        }
        uint4 v; v.x = pk[0]; v.y = pk[1]; v.z = pk[2]; v.w = pk[3];
        *(uint4*)&xq[((((size_t)(b * 8 + cb)) * XQPX_) + (rp * 2 + rr) * XQW_ + hc) * 32 + seg * 8] = v;
    }
}

// ---- conv staging: pure b128 copies from xq
__device__ __forceinline__ void stage_xq(const ushort* __restrict__ xq, short* __restrict__ dst,
                                         int b, int cb, int i0, int j0, int tid) {
    const ushort* base = xq + (((size_t)(b * 8 + cb)) * XQPX_) * 32;
    for (int e = tid; e < 400; e += 256) {           // 100 hpx x 4 segs of 8ci
        int hp = e >> 2, seg = e & 3;
        int hr = hp / 10, hc = hp - hr * 10;
        const ushort* src = base + ((size_t)((i0 + hr) * XQW_ + (j0 + hc))) * 32 + seg * 8;
        *(bh8*)&dst[hp * 72 + seg * 8] = *(const bh8*)src;
    }
}

// ---- conv 3x3 bf16 MFMA; 4 waves: wave = 32cc x 64px (m=2, n=4)  [round-5 best]
__global__ __launch_bounds__(256) void conv3x3_mfma(const ushort* __restrict__ xq,
                                                    const short* __restrict__ wg,
                                                    const float* __restrict__ bext,
                                                    ushort* __restrict__ fpad_t) {
    __shared__ __align__(16) short xh[2][100 * 72];   // 28.8 KB double-buffered
    const int tid = threadIdx.x;
    const int lane = tid & 63, wv = tid >> 6;
    const int j0 = blockIdx.x * 8, i0 = blockIdx.y * 8, b = blockIdx.z;
    const int l15 = lane & 15, kg = lane >> 4;
    const int cc0 = wv * 32;

    f4 acc[2][4] = {};

    stage_xq(xq, xh[0], b, 0, i0, j0, tid);
    __syncthreads();

    for (int cb = 0; cb < 8; ++cb) {
        const int buf = cb & 1;
        if (cb < 7) stage_xq(xq, xh[buf ^ 1], b, cb + 1, i0, j0, tid);

        const short* wbase = wg + (size_t)(cb * 9) * 128 * 32;
#pragma unroll
        for (int rs = 0; rs < 9; ++rs) {
            const int r = rs / 3, s = rs % 3;
            bh8 a[2], bb[4];
#pragma unroll
            for (int mm = 0; mm < 2; ++mm)
                a[mm] = *(const bh8*)(wbase + (rs * 128 + cc0 + mm * 16 + l15) * 32 + kg * 8);
#pragma unroll
            for (int nn = 0; nn < 4; ++nn) {
                int px = nn * 16 + l15, pi = px >> 3, pj = px & 7;
                int hidx = (pi + r) * 10 + (pj + s);
                bb[nn] = *(const bh8*)&xh[buf][hidx * 72 + kg * 8];
            }
#pragma unroll
            for (int mm = 0; mm < 2; ++mm)
#pragma unroll
                for (int nn = 0; nn < 4; ++nn)
                    acc[mm][nn] = __builtin_amdgcn_mfma_f32_16x16x32_bf16(
                        a[mm], bb[nn], acc[mm][nn], 0, 0, 0);
        }
        __syncthreads();
    }

    // epilogue: D row -> cc (kg*4+reg), col -> px; pack 4 cc -> 8B store
#pragma unroll
    for (int mm = 0; mm < 2; ++mm) {
        const int ccb = cc0 + mm * 16 + kg * 4;
        float bv0 = bext[ccb + 0], bv1 = bext[ccb + 1];
        float bv2 = bext[ccb + 2], bv3 = bext[ccb + 3];
#pragma unroll
        for (int nn = 0; nn < 4; ++nn) {
            int px = nn * 16 + l15, pi = px >> 3, pj = px & 7;
            size_t row = (size_t)b * HPX_ + (2 + i0 + pi) * HP_ + (2 + j0 + pj);
            uint lo = (uint)f2bf(acc[mm][nn][0] + bv0) | ((uint)f2bf(acc[mm][nn][1] + bv1) << 16);
            uint hi = (uint)f2bf(acc[mm][nn][2] + bv2) | ((uint)f2bf(acc[mm][nn][3] + bv3) << 16);
            uint2 pk; pk.x = lo; pk.y = hi;
            *(uint2*)&fpad_t[row * 128 + ccb] = pk;
        }
    }
}

// ---- autocorr bf16 MFMA; 4 waves: wave = 32o x 32px (m=2, n=2; oh/ph)  [round-5 best]
__global__ __launch_bounds__(256) void autocorr_mfma(const ushort* __restrict__ ft,
                                                     const short* __restrict__ wA,
                                                     const float* __restrict__ breg,
                                                     float* __restrict__ out) {
    __shared__ __align__(16) short flds[144 * 136];   // 39.2 KB
    const int tid = threadIdx.x;
    const int lane = tid & 63, wv = tid >> 6;
    const int oh = wv >> 1, ph = wv & 1;
    const int j0 = blockIdx.x * 8, i0 = blockIdx.y * 8, b = blockIdx.z;
    const int l15 = lane & 15, kg = lane >> 4;

    for (int e = tid; e < 2304; e += 256) {           // 144 hpx x 16 segs
        int hp = e >> 4, seg = e & 15;
        int hr = hp / 12, hc = hp - hr * 12;
        const ushort* src = ft + ((size_t)b * HPX_ + (i0 + hr) * HP_ + (j0 + hc)) * 128 + seg * 8;
        *(bh8*)&flds[hp * 136 + seg * 8] = *(const bh8*)src;
    }
    __syncthreads();

    f4 acc[2][2] = {};
    int base_off[2], cen_off[2];
#pragma unroll
    for (int t = 0; t < 2; ++t) {
        int px = ph * 32 + t * 16 + l15;
        int pi = px >> 3, pj = px & 7;
        base_off[t] = (pi * 12 + pj) * 136 + kg * 8;
        cen_off[t]  = ((pi + 2) * 12 + (pj + 2)) * 136 + kg * 8;
    }

#pragma unroll 1
    for (int q = 0; q < 4; ++q) {
        float cen[2][8];
#pragma unroll
        for (int t = 0; t < 2; ++t) {
            bh8 c8 = *(const bh8*)&flds[cen_off[t] + q * 32];
#pragma unroll
            for (int jj = 0; jj < 8; ++jj) cen[t][jj] = bf2f((ushort)c8[jj]);
        }
        const short* wq = wA + q * (25 * 64 * 32);
#pragma unroll
        for (int k = 0; k < 25; ++k) {
            const int u = k / 5, v = k % 5;
            const int koff = (u * 12 + v) * 136;
            bh8 a[2];
#pragma unroll
            for (int mm = 0; mm < 2; ++mm)
                a[mm] = *(const bh8*)(wq + (k * 64 + oh * 32 + mm * 16 + l15) * 32 + kg * 8);
            bh8 bb[2];
#pragma unroll
            for (int t = 0; t < 2; ++t) {
                bh8 s8 = *(const bh8*)&flds[base_off[t] + q * 32 + koff];
#pragma unroll
                for (int jj = 0; jj < 8; ++jj) {
                    float p = bf2f((ushort)s8[jj]) * cen[t][jj];
                    bb[t][jj] = f2bf_c(p);
                }
            }
#pragma unroll
            for (int mm = 0; mm < 2; ++mm)
#pragma unroll
                for (int t = 0; t < 2; ++t)
                    acc[mm][t] = __builtin_amdgcn_mfma_f32_16x16x32_bf16(
                        a[mm], bb[t], acc[mm][t], 0, 0, 0);
        }
    }

    // epilogue: D row -> o, col -> px
#pragma unroll
    for (int mm = 0; mm < 2; ++mm) {
#pragma unroll
        for (int reg = 0; reg < 4; ++reg) {
            int o = oh * 32 + mm * 16 + kg * 4 + reg;
            float bv = breg[o];
#pragma unroll
            for (int t = 0; t < 2; ++t) {
                int px = ph * 32 + t * 16 + l15, pi = px >> 3, pj = px & 7;
                out[(((size_t)(b * COUT_ + o)) * 64 + i0 + pi) * 64 + j0 + pj] =
                    acc[mm][t][reg] + bv;
            }
        }
    }
}

extern "C" void kernel_launch(void* const* d_in, const int* in_sizes, int n_in,
                              void* d_out, int out_size, void* d_ws, size_t ws_size,
                              hipStream_t stream) {
    const float* x     = (const float*)d_in[0];
    const float* w_ext = (const float*)d_in[1];
    const float* b_ext = (const float*)d_in[2];
    const float* w_reg = (const float*)d_in[3];
    const float* b_reg = (const float*)d_in[4];
    float* out = (float*)d_out;

    char* ws = (char*)d_ws;
    const size_t FPADT_BYTES = (size_t)B_ * HPX_ * 128 * 2;        // 9,469,952
    const size_t WG_BYTES    = (size_t)8 * 9 * 128 * 32 * 2;       // 589,824
    const size_t WA_BYTES    = (size_t)4 * 25 * 64 * 32 * 2;       // 409,600
    ushort* fpad_t = (ushort*)ws;
    short*  wgq    = (short*)(ws + FPADT_BYTES);
    short*  wa     = (short*)(ws + FPADT_BYTES + WG_BYTES);
    ushort* xq     = (ushort*)(ws + FPADT_BYTES + WG_BYTES + WA_BYTES);  // 17,842,176

    const int PREP_TOTAL = 67584 + 294912 + 204800;   // 567,296
    prep_misc<<<(PREP_TOTAL + 255) / 256, 256, 0, stream>>>(w_ext, w_reg, wgq, wa, fpad_t);

    dim3 pgrid(33, 8, 8);                             // row-pairs, cb, b
    prep_x<<<pgrid, 256, 0, stream>>>(x, xq);

    dim3 grid(8, 8, 8);
    conv3x3_mfma<<<grid, 256, 0, stream>>>(xq, wgq, b_ext, fpad_t);
    autocorr_mfma<<<grid, 256, 0, stream>>>(fpad_t, wa, b_reg, out);
}